// Round 1
// baseline (130.611 us; speedup 1.0000x reference)
//
#include <hip/hip_runtime.h>

// FeatureFlowAttention (local_window_attn=1, r=1), b=4, c=128, h=w=128.
// scores(p,p') = x_p^T M x_p' + gamma_p + delta_p' + d, M = Wq^T Wk.
// Pipeline (3 kernels):
//   prep:  M = Wq^T Wk split to bf16 (Mh,Ml); u, v, d.   (129 blocks: 1 ci-row/block)
//   proj:  y = M x via MFMA split-bf16 3-pass, zero LDS; cig0 waves also emit
//          gmap = u.x and dmap = v.x per pixel (shuffle-reduced over q-groups).
//   attn_fused: 9-shift scores (4-way channel split, 2 px/thread) combined in LDS,
//          validity-mask, softmax, flow gather — ps/gd never hit global memory.

#define HW 16384
#define NB 4
#define TOT (NB * HW)   // 65536 pixels

typedef short bf16x8 __attribute__((ext_vector_type(8)));
typedef float f32x4 __attribute__((ext_vector_type(4)));

__device__ __forceinline__ unsigned short f2bf(float f) {   // RNE float->bf16
    unsigned u = __float_as_uint(f);
    return (unsigned short)((u + 0x7fffu + ((u >> 16) & 1u)) >> 16);
}
__device__ __forceinline__ float bf2f(unsigned short s) {
    return __uint_as_float(((unsigned)s) << 16);
}

// ---------------- prep ----------------------------------------------------------
// blocks 0..127: M row ci = bid (256 thr: cj = tid&127, co-half = tid>>7, LDS combine)
// block 128: u, v, d (as before)
__global__ void prep_kernel(const float* __restrict__ qw, const float* __restrict__ qb,
                            const float* __restrict__ kw, const float* __restrict__ kb,
                            unsigned short* __restrict__ Mh, unsigned short* __restrict__ Ml,
                            float* __restrict__ u, float* __restrict__ v,
                            float* __restrict__ dptr) {
    __shared__ float red[128];
    int bid = blockIdx.x, tid = threadIdx.x;
    if (bid < 128) {
        int ci = bid;
        int cj = tid & 127, half = tid >> 7;
        int co0 = half * 64;
        const float* qcol = qw + ci;
        float acc = 0.f;
#pragma unroll 4
        for (int co = 0; co < 64; ++co)
            acc += qcol[(size_t)(co0 + co) * 128] * kw[(size_t)(co0 + co) * 128 + cj];
        if (half) red[cj] = acc;
        __syncthreads();
        if (!half) {
            float mval = acc + red[cj];
            unsigned short h = f2bf(mval);
            Mh[ci * 128 + cj] = h;
            Ml[ci * 128 + cj] = f2bf(mval - bf2f(h));
        }
    } else {
        // u[t] = sum qw[co][t]*kb[co];  v[t] = sum kw[co][t]*qb[co];  d = qb.kb
        int half = tid >> 7, t = tid & 127;
        const float* w  = half ? kw : qw;
        const float* bv = half ? qb : kb;
        float acc = 0.f;
#pragma unroll 4
        for (int co = 0; co < 128; ++co) acc += w[co * 128 + t] * bv[co];
        if (half) v[t] = acc; else u[t] = acc;
        if (!half) red[t] = qb[t] * kb[t];
        __syncthreads();
        if (tid == 0) {
            float dd = 0.f;
            for (int i = 0; i < 128; ++i) dd += red[i];
            *dptr = dd;
        }
    }
}

// ---------------- proj: y = M x via MFMA split-bf16, zero LDS + gmap/dmap --------
// Wave W: cig = W&3 (ci range cig*32..+32), pxg = W>>2 (64-px tile, within one image).
// Verified layouts (16x16x32 bf16): A[m=lane&15][k=(lane>>4)*8+j];
// B[k=(lane>>4)*8+j][n=lane&15]; D col=lane&15, row=(lane>>4)*4+reg.
// cig==0 waves additionally accumulate gamma=u.x, delta=v.x over their channels
// (each wave's kc loop covers ALL 128 channels) and shuffle-reduce over q-groups.
__global__ __launch_bounds__(256, 2)
void proj_kernel(const float* __restrict__ feat, const unsigned short* __restrict__ MhG,
                 const unsigned short* __restrict__ MlG,
                 const float* __restrict__ u, const float* __restrict__ v,
                 float* __restrict__ y, float* __restrict__ gmap, float* __restrict__ dmap) {
    int tid = threadIdx.x;
    int W = blockIdx.x * 4 + (tid >> 6);
    int lane = tid & 63;
    int cig = W & 3, pxg = W >> 2;
    int ci0 = cig * 32;
    int P0 = pxg * 64;
    int b = P0 >> 14, p0 = P0 & (HW - 1);
    int m = lane & 15, q = lane >> 4;
    const float* xbase = feat + (size_t)b * 128 * HW + p0;

    f32x4 zero = {0.f, 0.f, 0.f, 0.f};
    f32x4 acc[2][4];
#pragma unroll
    for (int t = 0; t < 2; ++t)
#pragma unroll
        for (int s = 0; s < 4; ++s) acc[t][s] = zero;

    float gacc[4] = {0.f, 0.f, 0.f, 0.f};
    float dacc[4] = {0.f, 0.f, 0.f, 0.f};

#pragma unroll
    for (int kc = 0; kc < 4; ++kc) {
        int c0 = kc * 32;
        bf16x8 ah[2], al[2];
#pragma unroll
        for (int t = 0; t < 2; ++t) {
            int roff = (ci0 + t * 16 + m) * 128 + c0 + q * 8;
            ah[t] = *(const bf16x8*)(MhG + roff);
            al[t] = *(const bf16x8*)(MlG + roff);
        }
        float uu[8], vv[8];
        if (cig == 0) {
#pragma unroll
            for (int j = 0; j < 8; ++j) {
                uu[j] = u[c0 + q * 8 + j];
                vv[j] = v[c0 + q * 8 + j];
            }
        }
        bf16x8 bh[4], bl[4];
#pragma unroll
        for (int s = 0; s < 4; ++s) {
            const float* xp = xbase + (size_t)(c0 + q * 8) * HW + s * 16 + m;
            float xv[8];
#pragma unroll
            for (int j = 0; j < 8; ++j) xv[j] = xp[(size_t)j * HW];
            if (cig == 0) {
#pragma unroll
                for (int j = 0; j < 8; ++j) {
                    gacc[s] += uu[j] * xv[j];
                    dacc[s] += vv[j] * xv[j];
                }
            }
#pragma unroll
            for (int j = 0; j < 8; ++j) {
                unsigned short h = f2bf(xv[j]);
                bh[s][j] = (short)h;
                bl[s][j] = (short)f2bf(xv[j] - bf2f(h));
            }
        }
#pragma unroll
        for (int t = 0; t < 2; ++t)
#pragma unroll
            for (int s = 0; s < 4; ++s) {
                acc[t][s] = __builtin_amdgcn_mfma_f32_16x16x32_bf16(ah[t], bh[s], acc[t][s], 0, 0, 0);
                acc[t][s] = __builtin_amdgcn_mfma_f32_16x16x32_bf16(ah[t], bl[s], acc[t][s], 0, 0, 0);
                acc[t][s] = __builtin_amdgcn_mfma_f32_16x16x32_bf16(al[t], bh[s], acc[t][s], 0, 0, 0);
            }
    }

    int rg = lane >> 4, col = lane & 15;
#pragma unroll
    for (int t = 0; t < 2; ++t)
#pragma unroll
        for (int s = 0; s < 4; ++s) {
            float* yp = y + ((size_t)b * 128 + ci0 + t * 16 + rg * 4) * HW + p0 + s * 16 + col;
#pragma unroll
            for (int r = 0; r < 4; ++r) yp[(size_t)r * HW] = acc[t][s][r];
        }

    if (cig == 0) {
        // reduce over q (lane bits 4,5); lanes 0..15 store 64 px of gamma/delta maps
#pragma unroll
        for (int s = 0; s < 4; ++s) {
            float gg = gacc[s];
            gg += __shfl_xor(gg, 16);
            gg += __shfl_xor(gg, 32);
            float dd = dacc[s];
            dd += __shfl_xor(dd, 16);
            dd += __shfl_xor(dd, 32);
            if (lane < 16) {
                gmap[P0 + s * 16 + lane] = gg;
                dmap[P0 + s * 16 + lane] = dd;
            }
        }
    }
}

// ---------------- attn_fused: partial scores + softmax + flow gather -------------
// 256 blocks x 512 threads. Main phase: cg = tid>>7 (32-ch group), pp = tid&127
// (pixel pair, block covers 256 px = 2 rows of one image). Partials meet in LDS.
// Epilogue: threads 0..255, one pixel each: sum 4 cg partials, add gamma/delta/d,
// mask invalid to 0 (zero-padded reference semantics), softmax, flow gather.
__global__ __launch_bounds__(512, 2)
void attn_fused_kernel(const float* __restrict__ feat, const float* __restrict__ y,
                       const float* __restrict__ gmap, const float* __restrict__ dmap,
                       const float* __restrict__ dptr, const float* __restrict__ flow,
                       float* __restrict__ out) {
    __shared__ float2 lds[4 * 9 * 128];   // 36 KB: [cg][k][pp] -> (s0,s1)
    int tid = threadIdx.x;
    int cg = tid >> 7;
    int pp = tid & 127;
    int P = blockIdx.x * 256 + pp * 2;    // even pixel of the pair
    int b = P >> 14;
    int p = P & (HW - 1);
    const float* xb = feat + ((size_t)b * 128 + cg * 32) * HW + p;
    const float* yb = y + ((size_t)b * 128 + cg * 32) * HW + p;

    float s0[9], s1[9];
#pragma unroll
    for (int k = 0; k < 9; ++k) { s0[k] = 0.f; s1[k] = 0.f; }

#pragma unroll 2
    for (int c = 0; c < 32; ++c) {
        float2 xv = *(const float2*)(xb + (size_t)c * HW);
        const float* yc = yb + (size_t)c * HW;
#pragma unroll
        for (int dy = 0; dy < 3; ++dy) {
            const float* yr = yc + (dy - 1) * 128;
            float2 a  = *(const float2*)(yr - 2);   // cols p-2,p-1
            float2 bb = *(const float2*)(yr);       // cols p,  p+1
            float2 cc = *(const float2*)(yr + 2);   // cols p+2,p+3
            s0[dy * 3 + 0] += xv.x * a.y;   s1[dy * 3 + 0] += xv.y * bb.x;
            s0[dy * 3 + 1] += xv.x * bb.x;  s1[dy * 3 + 1] += xv.y * bb.y;
            s0[dy * 3 + 2] += xv.x * bb.y;  s1[dy * 3 + 2] += xv.y * cc.x;
        }
    }
#pragma unroll
    for (int k = 0; k < 9; ++k)
        lds[(cg * 9 + k) * 128 + pp] = make_float2(s0[k], s1[k]);
    __syncthreads();

    if (tid < 256) {
        int P2 = blockIdx.x * 256 + tid;  // one pixel per thread
        int b2 = P2 >> 14, p2 = P2 & (HW - 1);
        int row = p2 >> 7, col = p2 & 127;
        const float inv = 0.08838834764831845f;   // 1/sqrt(128)
        float dconst = *dptr;
        float g = gmap[P2];
        const float* lf = (const float*)lds;      // float idx (cg*9+k)*256 + tid

        float sc[9];
        float mx = -1e30f;
#pragma unroll
        for (int k = 0; k < 9; ++k) {
            float ssum = lf[(0 * 9 + k) * 256 + tid] + lf[(1 * 9 + k) * 256 + tid]
                       + lf[(2 * 9 + k) * 256 + tid] + lf[(3 * 9 + k) * 256 + tid];
            int dy = k / 3 - 1, dx = (k % 3) - 1;
            bool valid = ((unsigned)(row + dy) < 128u) && ((unsigned)(col + dx) < 128u);
            int Pn = P2 + dy * 128 + dx;
            Pn = max(0, min(TOT - 1, Pn));
            float s = valid ? (ssum + g + dconst + dmap[Pn]) * inv : 0.f;
            sc[k] = s;
            mx = fmaxf(mx, s);
        }
        float e[9], sum = 0.f;
#pragma unroll
        for (int k = 0; k < 9; ++k) { e[k] = __expf(sc[k] - mx); sum += e[k]; }
        float rs = 1.f / sum;

        float o0 = 0.f, o1 = 0.f;
#pragma unroll
        for (int k = 0; k < 9; ++k) {
            int dy = k / 3 - 1, dx = (k % 3) - 1;
            bool valid = ((unsigned)(row + dy) < 128u) && ((unsigned)(col + dx) < 128u);
            float pr = valid ? e[k] * rs : 0.f;
            int fi0 = b2 * 2 * HW + p2 + dy * 128 + dx;
            fi0 = max(0, min(2 * TOT - 1, fi0));
            int fi1 = (b2 * 2 + 1) * HW + p2 + dy * 128 + dx;
            fi1 = max(0, min(2 * TOT - 1, fi1));
            o0 += pr * flow[fi0];
            o1 += pr * flow[fi1];
        }
        out[(size_t)(b2 * 2) * HW + p2] = o0;
        out[(size_t)(b2 * 2 + 1) * HW + p2] = o1;
    }
}

extern "C" void kernel_launch(void* const* d_in, const int* in_sizes, int n_in,
                              void* d_out, int out_size, void* d_ws, size_t ws_size,
                              hipStream_t stream) {
    const float* feat = (const float*)d_in[0];
    const float* flow = (const float*)d_in[1];
    const float* qw = (const float*)d_in[2];
    const float* qb = (const float*)d_in[3];
    const float* kw = (const float*)d_in[4];
    const float* kb = (const float*)d_in[5];

    float* ws = (float*)d_ws;
    float* u = ws;                              // 128
    float* v = ws + 128;                        // 128
    float* dptr = ws + 256;                     // 1 (pad to 512)
    unsigned short* Mh = (unsigned short*)(ws + 512);    // 16384 bf16 = 8192 fl
    unsigned short* Ml = (unsigned short*)(ws + 8704);   // 16384 bf16 = 8192 fl
    float* y = ws + 16896;                      // 4*128*16384 = 8388608 (+256 pad after)
    float* dmap = ws + 8405760;                 // 65536
    float* gmap = ws + 8471296;                 // 65536
    float* out = (float*)d_out;

    prep_kernel<<<129, 256, 0, stream>>>(qw, qb, kw, kb, Mh, Ml, u, v, dptr);
    proj_kernel<<<1024, 256, 0, stream>>>(feat, Mh, Ml, u, v, y, gmap, dmap);
    attn_fused_kernel<<<256, 512, 0, stream>>>(feat, y, gmap, dmap, dptr, flow, out);
}

// Round 2
// 116.609 us; speedup vs baseline: 1.1201x; 1.1201x over previous
//
#include <hip/hip_runtime.h>

// FeatureFlowAttention (local_window_attn=1, r=1), b=4, c=128, h=w=128.
// score(p,p') = x_p^T M x_p' + gamma_p + delta_p' + d,  M = Wq^T Wk.
// Transposed-form fusion: z_p = M^T x_p + v  (own-pixel only -> no halo GEMM,
// no global y). score_k(p) = z_p . x_{p+dk} + gamma_p + d (valid; else 0).
// Pipeline (2 kernels):
//   prep:  MT = (Wq^T Wk)^T split to bf16 (MhT,MlT); u, v, d.
//   fused: per image-row block (512 thr): stage MT in LDS (XOR-swizzled) ->
//          MFMA split-bf16 z for 128 px -> z to LDS (rotated) -> 4-way-ch-split
//          score vs x-halo -> LDS combine -> softmax -> flow gather.

#define HW 16384
#define NB 4
#define TOT (NB * HW)   // 65536 pixels

typedef short bf16x8 __attribute__((ext_vector_type(8)));
typedef float f32x4 __attribute__((ext_vector_type(4)));

__device__ __forceinline__ unsigned short f2bf(float f) {   // RNE float->bf16
    unsigned u = __float_as_uint(f);
    return (unsigned short)((u + 0x7fffu + ((u >> 16) & 1u)) >> 16);
}
__device__ __forceinline__ float bf2f(unsigned short s) {
    return __uint_as_float(((unsigned)s) << 16);
}

// ---------------- prep ----------------------------------------------------------
// blocks 0..127: MT row ci = bid:  MT[ci][cj] = sum_co kw[co][ci]*qw[co][cj]
// block 128: u[t] = sum qw[co][t]*kb[co]; v[t] = sum kw[co][t]*qb[co]; d = qb.kb
__global__ void prep_kernel(const float* __restrict__ qw, const float* __restrict__ qb,
                            const float* __restrict__ kw, const float* __restrict__ kb,
                            unsigned short* __restrict__ MhT, unsigned short* __restrict__ MlT,
                            float* __restrict__ u, float* __restrict__ v,
                            float* __restrict__ dptr) {
    __shared__ float red[128];
    int bid = blockIdx.x, tid = threadIdx.x;
    if (bid < 128) {
        int ci = bid;
        int cj = tid & 127, half = tid >> 7;
        int co0 = half * 64;
        const float* kcol = kw + ci;
        float acc = 0.f;
#pragma unroll 4
        for (int co = 0; co < 64; ++co)
            acc += kcol[(size_t)(co0 + co) * 128] * qw[(size_t)(co0 + co) * 128 + cj];
        if (half) red[cj] = acc;
        __syncthreads();
        if (!half) {
            float mval = acc + red[cj];
            unsigned short h = f2bf(mval);
            MhT[ci * 128 + cj] = h;
            MlT[ci * 128 + cj] = f2bf(mval - bf2f(h));
        }
    } else {
        int half = tid >> 7, t = tid & 127;
        const float* w  = half ? kw : qw;
        const float* bv = half ? qb : kb;
        float acc = 0.f;
#pragma unroll 4
        for (int co = 0; co < 128; ++co) acc += w[co * 128 + t] * bv[co];
        if (half) v[t] = acc; else u[t] = acc;
        if (!half) red[t] = qb[t] * kb[t];
        __syncthreads();
        if (tid == 0) {
            float dd = 0.f;
            for (int i = 0; i < 128; ++i) dd += red[i];
            *dptr = dd;
        }
    }
}

// ---------------- fused ---------------------------------------------------------
// Grid 512 = 4 images x 128 rows. Block 512 thr (8 waves).
// Phase A: stage MhT/MlT (64 KB) into LDS, XOR-swizzled: byte ^= ((ci&7)<<4).
// Phase B: GEMM z = MT x + v. Wave w: 16 px (wp0=w*16), all 128 ci.
//   Verified layouts (16x16x32 bf16): A[m=lane&15][k=(lane>>4)*8+j];
//   B[k=(lane>>4)*8+j][n=lane&15]; D col=lane&15, row=(lane>>4)*4+reg.
//   z -> LDS (overwrites MT region) at [px][(c+px)&127]  (rotation: 2-way banks).
// Phase C: score. thread: px=tid&127, h=tid>>7 handles 32 channels.
//   sc[9] partials + gamma partial -> LDS overlay (after barrier) -> tid<128:
//   combine, validity mask (invalid score = 0, kept in softmax denom, excluded
//   from numerator -- zero-pad semantics), softmax, flow gather.
__global__ __launch_bounds__(512, 4)
void fused_kernel(const float* __restrict__ feat,
                  const unsigned short* __restrict__ MhT, const unsigned short* __restrict__ MlT,
                  const float* __restrict__ u, const float* __restrict__ v,
                  const float* __restrict__ dptr, const float* __restrict__ flow,
                  float* __restrict__ out) {
    __shared__ float zbuf[16384];   // 64 KB, multi-purpose
    int tid = threadIdx.x;
    int bid = blockIdx.x;
    int b = bid >> 7, row = bid & 127;
    int p0 = row * 128;

    // ---- Phase A: stage swizzled MT into LDS (Mh at byte 0, Ml at byte 32768)
    {
        char* lbase = (char*)zbuf;
#pragma unroll
        for (int it = 0; it < 4; ++it) {
            int chunk = it * 512 + tid;            // 2048 x 16B chunks = 32 KB
            int off = chunk * 16;                  // byte offset in Mh half
            int swz = off ^ (((off >> 8) & 7) << 4);
            bf16x8 tv = *(const bf16x8*)((const char*)MhT + off);
            *(bf16x8*)(lbase + swz) = tv;
            bf16x8 tv2 = *(const bf16x8*)((const char*)MlT + off);
            *(bf16x8*)(lbase + 32768 + swz) = tv2;
        }
    }
    __syncthreads();

    // ---- Phase B: GEMM
    {
        int wave = tid >> 6, lane = tid & 63;
        int m = lane & 15, q = lane >> 4;
        int wp0 = wave * 16;
        const float* xbase = feat + (size_t)b * 128 * HW + p0 + wp0;
        const char* lbase = (const char*)zbuf;

        f32x4 zero = {0.f, 0.f, 0.f, 0.f};
        f32x4 acc[8];
#pragma unroll
        for (int t = 0; t < 8; ++t) acc[t] = zero;

#pragma unroll
        for (int kc = 0; kc < 4; ++kc) {
            int c0 = kc * 32;
            // B-frag from x (in-register bf16 split)
            const float* xp = xbase + (size_t)(c0 + q * 8) * HW + m;
            float xv[8];
#pragma unroll
            for (int j = 0; j < 8; ++j) xv[j] = xp[(size_t)j * HW];
            bf16x8 bh, bl;
#pragma unroll
            for (int j = 0; j < 8; ++j) {
                unsigned short hh = f2bf(xv[j]);
                bh[j] = (short)hh;
                bl[j] = (short)f2bf(xv[j] - bf2f(hh));
            }
            // A-frags from swizzled LDS, 8 ci-tiles
            int colb = (c0 + q * 8) * 2;
            int swzx = ((m & 7) << 4);
#pragma unroll
            for (int t = 0; t < 8; ++t) {
                int offr = ((t * 16 + m) * 256 + colb) ^ swzx;
                bf16x8 ah = *(const bf16x8*)(lbase + offr);
                bf16x8 al = *(const bf16x8*)(lbase + 32768 + offr);
                acc[t] = __builtin_amdgcn_mfma_f32_16x16x32_bf16(ah, bh, acc[t], 0, 0, 0);
                acc[t] = __builtin_amdgcn_mfma_f32_16x16x32_bf16(ah, bl, acc[t], 0, 0, 0);
                acc[t] = __builtin_amdgcn_mfma_f32_16x16x32_bf16(al, bh, acc[t], 0, 0, 0);
            }
        }
        __syncthreads();   // done reading MT from LDS
        // epilogue: z = acc + v -> zbuf[px][(c+px)&127]
        int px = wp0 + (lane & 15);
        int rg = lane >> 4;
#pragma unroll
        for (int t = 0; t < 8; ++t)
#pragma unroll
            for (int r = 0; r < 4; ++r) {
                int c = t * 16 + rg * 4 + r;
                zbuf[px * 128 + ((c + px) & 127)] = acc[t][r] + v[c];
            }
    }
    __syncthreads();

    // ---- Phase C: score partials
    {
        int spx = tid & 127, h = tid >> 7;
        int p = p0 + spx;
        float sc[9];
#pragma unroll
        for (int k = 0; k < 9; ++k) sc[k] = 0.f;
        float g = 0.f;
#pragma unroll 2
        for (int cc = 0; cc < 32; ++cc) {
            int c = h * 32 + cc;
            float zv = zbuf[spx * 128 + ((c + spx) & 127)];
            const float* xc = feat + ((size_t)b * 128 + c) * HW;
            float xcen = 0.f;
#pragma unroll
            for (int dy = 0; dy < 3; ++dy) {
                int off = p + (dy - 1) * 128;
                int om = max(0, min(HW - 1, off - 1));
                int oc = max(0, min(HW - 1, off));
                int op = max(0, min(HW - 1, off + 1));
                float xm = xc[om], x0 = xc[oc], xp1 = xc[op];
                sc[dy * 3 + 0] += zv * xm;
                sc[dy * 3 + 1] += zv * x0;
                sc[dy * 3 + 2] += zv * xp1;
                if (dy == 1) xcen = x0;
            }
            g += u[c] * xcen;
        }
        __syncthreads();   // all z reads complete; overlay partials
#pragma unroll
        for (int k = 0; k < 9; ++k)
            zbuf[(k * 128 + spx) * 4 + h] = sc[k];
        zbuf[(9 * 128 + spx) * 4 + h] = g;
    }
    __syncthreads();

    // ---- Phase D: combine + softmax + flow gather (threads 0..127)
    if (tid < 128) {
        int spx = tid;
        int p = p0 + spx;
        int col = spx;
        const float inv = 0.08838834764831845f;   // 1/sqrt(128)
        float dconst = *dptr;
        float g = zbuf[(9 * 128 + spx) * 4 + 0] + zbuf[(9 * 128 + spx) * 4 + 1]
                + zbuf[(9 * 128 + spx) * 4 + 2] + zbuf[(9 * 128 + spx) * 4 + 3];

        float sc[9];
        float mx = -1e30f;
#pragma unroll
        for (int k = 0; k < 9; ++k) {
            int dy = k / 3 - 1, dx = (k % 3) - 1;
            float ssum = zbuf[(k * 128 + spx) * 4 + 0] + zbuf[(k * 128 + spx) * 4 + 1]
                       + zbuf[(k * 128 + spx) * 4 + 2] + zbuf[(k * 128 + spx) * 4 + 3];
            bool valid = ((unsigned)(row + dy) < 128u) && ((unsigned)(col + dx) < 128u);
            float s = valid ? (ssum + g + dconst) * inv : 0.f;
            sc[k] = s;
            mx = fmaxf(mx, s);
        }
        float e[9], sum = 0.f;
#pragma unroll
        for (int k = 0; k < 9; ++k) { e[k] = __expf(sc[k] - mx); sum += e[k]; }
        float rs = 1.f / sum;

        float o0 = 0.f, o1 = 0.f;
#pragma unroll
        for (int k = 0; k < 9; ++k) {
            int dy = k / 3 - 1, dx = (k % 3) - 1;
            bool valid = ((unsigned)(row + dy) < 128u) && ((unsigned)(col + dx) < 128u);
            float pr = valid ? e[k] * rs : 0.f;
            int poff = p + dy * 128 + dx;
            poff = max(0, min(HW - 1, poff));
            o0 += pr * flow[(size_t)(b * 2) * HW + poff];
            o1 += pr * flow[(size_t)(b * 2 + 1) * HW + poff];
        }
        out[(size_t)(b * 2) * HW + p] = o0;
        out[(size_t)(b * 2 + 1) * HW + p] = o1;
    }
}

extern "C" void kernel_launch(void* const* d_in, const int* in_sizes, int n_in,
                              void* d_out, int out_size, void* d_ws, size_t ws_size,
                              hipStream_t stream) {
    const float* feat = (const float*)d_in[0];
    const float* flow = (const float*)d_in[1];
    const float* qw = (const float*)d_in[2];
    const float* qb = (const float*)d_in[3];
    const float* kw = (const float*)d_in[4];
    const float* kb = (const float*)d_in[5];

    float* ws = (float*)d_ws;
    float* u = ws;                              // 128
    float* v = ws + 128;                        // 128
    float* dptr = ws + 256;                     // 1 (pad to 512)
    unsigned short* MhT = (unsigned short*)(ws + 512);    // 16384 bf16 = 8192 fl
    unsigned short* MlT = (unsigned short*)(ws + 8704);   // 16384 bf16 = 8192 fl
    float* out = (float*)d_out;

    prep_kernel<<<129, 256, 0, stream>>>(qw, qb, kw, kb, MhT, MlT, u, v, dptr);
    fused_kernel<<<512, 512, 0, stream>>>(feat, MhT, MlT, u, v, dptr, flow, out);
}

// Round 3
// 108.778 us; speedup vs baseline: 1.2007x; 1.0720x over previous
//
#include <hip/hip_runtime.h>

// FeatureFlowAttention (local_window_attn=1, r=1), b=4, c=128, h=w=128.
// score(p,p') = x_p^T M x_p' + gamma_p + delta_p' + d,  M = Wq^T Wk.
// Transposed form: z_p = M^T x_p + v  ->  score_k(p) = z_p . x_{p+dk} + gamma_p + d.
// Pipeline (2 kernels):
//   prep:  MT = (Wq^T Wk)^T split to bf16 (MhT,MlT); u, v, d.
//   fused: per image-row block (512 thr, XCD-chunked rowid): stage MT in LDS
//          (XOR-swizzled) -> MFMA split-bf16 z kept IN REGISTERS (lane owns 1 px
//          x 32 ch) -> score vs x-halo with hoisted row/col clamps (clamped
//          addresses only feed masked entries) -> shfl_xor channel reduce ->
//          softmax -> flow gather. One barrier total; z never touches LDS.

#define HW 16384
#define NB 4
#define TOT (NB * HW)   // 65536 pixels

typedef short bf16x8 __attribute__((ext_vector_type(8)));
typedef float f32x4 __attribute__((ext_vector_type(4)));

__device__ __forceinline__ unsigned short f2bf(float f) {   // RNE float->bf16
    unsigned u = __float_as_uint(f);
    return (unsigned short)((u + 0x7fffu + ((u >> 16) & 1u)) >> 16);
}
__device__ __forceinline__ float bf2f(unsigned short s) {
    return __uint_as_float(((unsigned)s) << 16);
}

// ---------------- prep ----------------------------------------------------------
// blocks 0..127: MT row ci = bid:  MT[ci][cj] = sum_co kw[co][ci]*qw[co][cj]
// block 128: u[t] = sum qw[co][t]*kb[co]; v[t] = sum kw[co][t]*qb[co]; d = qb.kb
__global__ void prep_kernel(const float* __restrict__ qw, const float* __restrict__ qb,
                            const float* __restrict__ kw, const float* __restrict__ kb,
                            unsigned short* __restrict__ MhT, unsigned short* __restrict__ MlT,
                            float* __restrict__ u, float* __restrict__ v,
                            float* __restrict__ dptr) {
    __shared__ float red[128];
    int bid = blockIdx.x, tid = threadIdx.x;
    if (bid < 128) {
        int ci = bid;
        int cj = tid & 127, half = tid >> 7;
        int co0 = half * 64;
        const float* kcol = kw + ci;
        float acc = 0.f;
#pragma unroll 4
        for (int co = 0; co < 64; ++co)
            acc += kcol[(size_t)(co0 + co) * 128] * qw[(size_t)(co0 + co) * 128 + cj];
        if (half) red[cj] = acc;
        __syncthreads();
        if (!half) {
            float mval = acc + red[cj];
            unsigned short h = f2bf(mval);
            MhT[ci * 128 + cj] = h;
            MlT[ci * 128 + cj] = f2bf(mval - bf2f(h));
        }
    } else {
        int half = tid >> 7, t = tid & 127;
        const float* w  = half ? kw : qw;
        const float* bv = half ? qb : kb;
        float acc = 0.f;
#pragma unroll 4
        for (int co = 0; co < 128; ++co) acc += w[co * 128 + t] * bv[co];
        if (half) v[t] = acc; else u[t] = acc;
        if (!half) red[t] = qb[t] * kb[t];
        __syncthreads();
        if (tid == 0) {
            float dd = 0.f;
            for (int i = 0; i < 128; ++i) dd += red[i];
            *dptr = dd;
        }
    }
}

// ---------------- fused ---------------------------------------------------------
// Grid 512 = 4 images x 128 rows, XCD-chunked: rowid = (bid&7)*64 + (bid>>3) so
// each XCD's 64 co-resident blocks cover a contiguous row band (halo L2-hits).
// Verified layouts (16x16x32 bf16): A[m=lane&15][k=(lane>>4)*8+j];
// B[k=(lane>>4)*8+j][n=lane&15]; D col=lane&15, row=(lane>>4)*4+reg.
// Wave w: 16 px (cols w*16..w*16+15); lane: px col=w*16+(lane&15), channel set
// c = t*16 + q*4 + r (q=lane>>4, t=0..7, r=0..3) -> 32 z values in acc regs.
__global__ __launch_bounds__(512, 4)
void fused_kernel(const float* __restrict__ feat,
                  const unsigned short* __restrict__ MhT, const unsigned short* __restrict__ MlT,
                  const float* __restrict__ u, const float* __restrict__ v,
                  const float* __restrict__ dptr, const float* __restrict__ flow,
                  float* __restrict__ out) {
    __shared__ char lds[65536];   // swizzled MhT (0..32767) + MlT (32768..65535)
    int tid = threadIdx.x;
    int bid = blockIdx.x;
    int rowid = (bid & 7) * 64 + (bid >> 3);
    int b = rowid >> 7, row = rowid & 127;
    int p0 = row * 128;

    // ---- Phase A: stage swizzled MT into LDS. byte swizzle: off ^= ((ci&7)<<4)
#pragma unroll
    for (int it = 0; it < 4; ++it) {
        int off = (it * 512 + tid) * 16;           // byte offset in 32 KB half
        int swz = off ^ (((off >> 8) & 7) << 4);
        *(bf16x8*)(lds + swz) = *(const bf16x8*)((const char*)MhT + off);
        *(bf16x8*)(lds + 32768 + swz) = *(const bf16x8*)((const char*)MlT + off);
    }
    __syncthreads();   // the kernel's only barrier

    int wave = tid >> 6, lane = tid & 63;
    int m = lane & 15, q = lane >> 4;
    int col = wave * 16 + m;                       // column within the row
    const float* xbase = feat + (size_t)b * 128 * HW + p0 + wave * 16;

    // ---- Phase B: z = M^T x + v (in registers)
    f32x4 zero = {0.f, 0.f, 0.f, 0.f};
    f32x4 acc[8];
#pragma unroll
    for (int t = 0; t < 8; ++t) acc[t] = zero;

#pragma unroll
    for (int kc = 0; kc < 4; ++kc) {
        int c0 = kc * 32;
        const float* xp = xbase + (size_t)(c0 + q * 8) * HW + m;
        float xv[8];
#pragma unroll
        for (int j = 0; j < 8; ++j) xv[j] = xp[(size_t)j * HW];
        bf16x8 bh, bl;
#pragma unroll
        for (int j = 0; j < 8; ++j) {
            unsigned short hh = f2bf(xv[j]);
            bh[j] = (short)hh;
            bl[j] = (short)f2bf(xv[j] - bf2f(hh));
        }
        int colb = (c0 + q * 8) * 2;
        int swzx = (m & 7) << 4;
#pragma unroll
        for (int t = 0; t < 8; ++t) {
            int offr = ((t * 16 + m) * 256 + colb) ^ swzx;
            bf16x8 ah = *(const bf16x8*)(lds + offr);
            bf16x8 al = *(const bf16x8*)(lds + 32768 + offr);
            acc[t] = __builtin_amdgcn_mfma_f32_16x16x32_bf16(ah, bh, acc[t], 0, 0, 0);
            acc[t] = __builtin_amdgcn_mfma_f32_16x16x32_bf16(ah, bl, acc[t], 0, 0, 0);
            acc[t] = __builtin_amdgcn_mfma_f32_16x16x32_bf16(al, bh, acc[t], 0, 0, 0);
        }
    }
    // z = acc + v  (delta bias folded into z; neighbor dot then includes delta_p')
#pragma unroll
    for (int t = 0; t < 8; ++t) {
        float4 vv = *(const float4*)(v + t * 16 + q * 4);
#pragma unroll
        for (int r = 0; r < 4; ++r) acc[t][r] += ((const float*)&vv)[r];
    }

    // ---- Phase C: 9-shift scores + gamma, hoisted clamps (clamped -> masked)
    int a0 = (row > 0 ? row - 1 : 0) * 128;
    int a1 = row * 128;
    int a2 = (row < 127 ? row + 1 : 127) * 128;
    int cm = col > 0 ? col - 1 : 0;
    int cp = col < 127 ? col + 1 : 127;
    const float* fb = feat + (size_t)b * 128 * HW;

    float sc[9];
#pragma unroll
    for (int k = 0; k < 9; ++k) sc[k] = 0.f;
    float g = 0.f;

#pragma unroll
    for (int t = 0; t < 8; ++t) {
        float4 uu = *(const float4*)(u + t * 16 + q * 4);
#pragma unroll
        for (int r = 0; r < 4; ++r) {
            float zv = acc[t][r];
            const float* xc = fb + (size_t)(t * 16 + q * 4 + r) * HW;
            // dy = 0
            {
                const float* xr = xc + a0;
                sc[0] += zv * xr[cm]; sc[1] += zv * xr[col]; sc[2] += zv * xr[cp];
            }
            // dy = 1 (center row; also feeds gamma)
            {
                const float* xr = xc + a1;
                float x0 = xr[col];
                sc[3] += zv * xr[cm]; sc[4] += zv * x0; sc[5] += zv * xr[cp];
                g += ((const float*)&uu)[r] * x0;
            }
            // dy = 2
            {
                const float* xr = xc + a2;
                sc[6] += zv * xr[cm]; sc[7] += zv * xr[col]; sc[8] += zv * xr[cp];
            }
        }
    }

    // ---- channel reduce across the 4 q-groups (lane bits 4,5)
#pragma unroll
    for (int k = 0; k < 9; ++k) {
        sc[k] += __shfl_xor(sc[k], 16);
        sc[k] += __shfl_xor(sc[k], 32);
    }
    g += __shfl_xor(g, 16);
    g += __shfl_xor(g, 32);

    // ---- softmax + flow gather (all lanes compute; q==0 lanes store)
    const float inv = 0.08838834764831845f;       // 1/sqrt(128)
    float base = g + *dptr;
    bool rok0 = row > 0, rok2 = row < 127;
    bool cok0 = col > 0, cok2 = col < 127;
    bool vmask[9] = { rok0 && cok0, rok0, rok0 && cok2,
                      cok0,         true, cok2,
                      rok2 && cok0, rok2, rok2 && cok2 };

    float s[9];
    float mx = -1e30f;
#pragma unroll
    for (int k = 0; k < 9; ++k) {
        float sv = vmask[k] ? (sc[k] + base) * inv : 0.f;
        s[k] = sv;
        mx = fmaxf(mx, sv);
    }
    float e[9], sum = 0.f;
#pragma unroll
    for (int k = 0; k < 9; ++k) { e[k] = __expf(s[k] - mx); sum += e[k]; }
    float rs = 1.f / sum;

    const float* f0 = flow + (size_t)(b * 2) * HW;
    const float* f1 = f0 + HW;
    int av[3] = {a0, a1, a2};
    int cv[3] = {cm, col, cp};
    float o0 = 0.f, o1 = 0.f;
#pragma unroll
    for (int dy = 0; dy < 3; ++dy)
#pragma unroll
        for (int dx = 0; dx < 3; ++dx) {
            int k = dy * 3 + dx;
            float pr = vmask[k] ? e[k] * rs : 0.f;
            int off = av[dy] + cv[dx];
            o0 += pr * f0[off];
            o1 += pr * f1[off];
        }
    if (q == 0) {
        out[(size_t)(b * 2) * HW + p0 + col] = o0;
        out[(size_t)(b * 2 + 1) * HW + p0 + col] = o1;
    }
}

extern "C" void kernel_launch(void* const* d_in, const int* in_sizes, int n_in,
                              void* d_out, int out_size, void* d_ws, size_t ws_size,
                              hipStream_t stream) {
    const float* feat = (const float*)d_in[0];
    const float* flow = (const float*)d_in[1];
    const float* qw = (const float*)d_in[2];
    const float* qb = (const float*)d_in[3];
    const float* kw = (const float*)d_in[4];
    const float* kb = (const float*)d_in[5];

    float* ws = (float*)d_ws;
    float* u = ws;                              // 128
    float* v = ws + 128;                        // 128
    float* dptr = ws + 256;                     // 1 (pad to 512)
    unsigned short* MhT = (unsigned short*)(ws + 512);    // 16384 bf16 = 8192 fl
    unsigned short* MlT = (unsigned short*)(ws + 8704);   // 16384 bf16 = 8192 fl
    float* out = (float*)d_out;

    prep_kernel<<<129, 256, 0, stream>>>(qw, qb, kw, kb, MhT, MlT, u, v, dptr);
    fused_kernel<<<512, 512, 0, stream>>>(feat, MhT, MlT, u, v, dptr, flow, out);
}